// Round 1
// baseline (242.244 us; speedup 1.0000x reference)
//
#include <hip/hip_runtime.h>

// Head: B=4, T=4096, C=1024, H=64. out = softmax(causal((x@Wq+bq)@(x@Wk+bk)^T * C^-0.5)) @ (x@Wv+bv)
#define B_ 4
#define T_ 4096
#define C_ 1024
#define H_ 64
// C^-0.5 * log2(e): folds softmax scale into Q, and moves softmax into exp2 domain.
#define QSCALE 0.045084220027780106f

typedef float  f32x4  __attribute__((ext_vector_type(4)));
typedef __bf16 bf16x8 __attribute__((ext_vector_type(8)));
typedef __bf16 bf16x4 __attribute__((ext_vector_type(4)));

#define MFMA16(a, b, c) __builtin_amdgcn_mfma_f32_16x16x32_bf16((a), (b), (c), 0, 0, 0)

// ---------------------------------------------------------------------------
// prep: Wt[mat][n][k] = W_mat[k][n] as bf16.  mat: 0=K,1=Q,2=V.
// ---------------------------------------------------------------------------
__global__ __launch_bounds__(256) void prep_wt(const float* __restrict__ Wk,
                                               const float* __restrict__ Wq,
                                               const float* __restrict__ Wv,
                                               __bf16* __restrict__ Wt) {
    int idx = blockIdx.x * 256 + threadIdx.x;   // 0 .. 3*64*1024-1
    int mat = idx >> 16;
    int rem = idx & 65535;
    int n = rem & 63;        // inner: coalesced read of W[k][n]
    int k = rem >> 6;
    const float* W = (mat == 0) ? Wk : ((mat == 1) ? Wq : Wv);
    Wt[(size_t)mat * 65536 + (size_t)n * 1024 + k] = (__bf16)W[k * 64 + n];
}

// ---------------------------------------------------------------------------
// proj: q,k,v = x@W + b.  256 blocks x 256 threads (4 waves), 16 rows/wave.
// A-frag (x rows) and B-frag (Wt rows) loaded directly (16B/lane, L2-resident W).
// ---------------------------------------------------------------------------
__global__ __launch_bounds__(256) void proj_qkv(const float* __restrict__ x,
                                                const __bf16* __restrict__ Wt,
                                                const float* __restrict__ bk,
                                                const float* __restrict__ bq,
                                                const float* __restrict__ bv,
                                                __bf16* __restrict__ Kg,
                                                __bf16* __restrict__ Qg,
                                                __bf16* __restrict__ Vt) {
    int tid  = threadIdx.x;
    int w    = tid >> 6;
    int lane = tid & 63;
    int lo = lane & 15, g = lane >> 4;

    int arow = blockIdx.x * 64 + w * 16 + lo;       // A-fragment row (x row)
    const float* xrow = x + (size_t)arow * C_;

    f32x4 acc[3][4];
#pragma unroll
    for (int m = 0; m < 3; ++m)
#pragma unroll
        for (int n = 0; n < 4; ++n) acc[m][n] = (f32x4){0.f, 0.f, 0.f, 0.f};

    for (int kk = 0; kk < C_; kk += 32) {
        const float* xp = xrow + kk + g * 8;        // lane's 8 consecutive k
        f32x4 a0 = *(const f32x4*)(xp);
        f32x4 a1 = *(const f32x4*)(xp + 4);
        bf16x8 av;
        av[0] = (__bf16)a0[0]; av[1] = (__bf16)a0[1];
        av[2] = (__bf16)a0[2]; av[3] = (__bf16)a0[3];
        av[4] = (__bf16)a1[0]; av[5] = (__bf16)a1[1];
        av[6] = (__bf16)a1[2]; av[7] = (__bf16)a1[3];
#pragma unroll
        for (int mat = 0; mat < 3; ++mat) {
#pragma unroll
            for (int nt = 0; nt < 4; ++nt) {
                bf16x8 bv8 = *(const bf16x8*)(Wt + (size_t)(mat * 64 + nt * 16 + lo) * C_ + kk + g * 8);
                acc[mat][nt] = MFMA16(av, bv8, acc[mat][nt]);
            }
        }
    }

    // epilogue: D rows = 4*g + r (C/D layout: col = lane&15, row = (lane>>4)*4+reg)
    int rbase = blockIdx.x * 64 + w * 16 + 4 * g;
    const float* biases[3] = {bk, bq, bv};
#pragma unroll
    for (int mat = 0; mat < 3; ++mat) {
#pragma unroll
        for (int nt = 0; nt < 4; ++nt) {
            int h = nt * 16 + lo;
            float bb = biases[mat][h];
            if (mat == 2) {                          // V -> transposed [B][64][T]
                bf16x4 pk;
#pragma unroll
                for (int r = 0; r < 4; ++r) pk[r] = (__bf16)(acc[2][nt][r] + bb);
                int bb_ = rbase >> 12;
                int t0  = rbase & (T_ - 1);
                *(bf16x4*)(Vt + (size_t)(bb_ * 64 + h) * T_ + t0) = pk;
            } else {
                __bf16* dst = (mat == 0) ? Kg : Qg;
#pragma unroll
                for (int r = 0; r < 4; ++r) {
                    float v = acc[mat][nt][r] + bb;
                    if (mat == 1) v *= QSCALE;       // fold C^-0.5*log2(e) into Q
                    dst[(size_t)(rbase + r) * H_ + h] = (__bf16)v;
                }
            }
        }
    }
}

// ---------------------------------------------------------------------------
// attn: flash attention, 1 wave/block, 16 q rows/wave, KBLK=64.
// Swapped QK^T: St[k][q] = mfma(K, Q^T) so the softmax row (k axis) is
// lane-local (4 regs x 4 lane-groups) -> reduce = 15 fmax + 2 shfl_xor.
// ---------------------------------------------------------------------------
__global__ __launch_bounds__(64) void attn_fwd(const __bf16* __restrict__ Qg,
                                               const __bf16* __restrict__ Kg,
                                               const __bf16* __restrict__ Vt,
                                               float* __restrict__ out) {
    __shared__ alignas(16) __bf16 Plds[16 * 64];   // wave-private P re-layout buf
    char* pl = (char*)Plds;

    int bid = blockIdx.x;
    int b   = bid >> 8;
    int qt  = 255 - (bid & 255);                   // heavy tiles launch first
    int q0  = qt * 16;
    int lane = threadIdx.x;
    int lo = lane & 15, g = lane >> 4;

    // Q as B-fragment: lane holds Q[q0+lo][c*32 + g*8 + j]  (already *QSCALE)
    const __bf16* qp = Qg + (size_t)(b * T_ + q0 + lo) * H_ + g * 8;
    bf16x8 qb0 = *(const bf16x8*)(qp);
    bf16x8 qb1 = *(const bf16x8*)(qp + 32);

    f32x4 acc[4];
#pragma unroll
    for (int ht = 0; ht < 4; ++ht) acc[ht] = (f32x4){0.f, 0.f, 0.f, 0.f};
    float m = -1e30f, l = 0.f;

    int niter = ((q0 + 15) >> 6) + 1;              // only final iter needs mask
    for (int it = 0; it < niter; ++it) {
        int k0 = it << 6;
        f32x4 st[4];
#pragma unroll
        for (int kt = 0; kt < 4; ++kt) {
            const __bf16* kp = Kg + (size_t)(b * T_ + k0 + kt * 16 + lo) * H_ + g * 8;
            bf16x8 ka0 = *(const bf16x8*)(kp);
            bf16x8 ka1 = *(const bf16x8*)(kp + 32);
            f32x4 z = (f32x4){0.f, 0.f, 0.f, 0.f};
            z = MFMA16(ka0, qb0, z);               // St[k][q]: col=q=lo, row=k=4g+r
            z = MFMA16(ka1, qb1, z);
            st[kt] = z;
        }
        if (it == niter - 1) {                     // causal mask (partial tile)
#pragma unroll
            for (int kt = 0; kt < 4; ++kt)
#pragma unroll
                for (int r = 0; r < 4; ++r) {
                    int kabs = k0 + kt * 16 + 4 * g + r;
                    if (kabs > q0 + lo) st[kt][r] = -1e30f;
                }
        }
        // online softmax (exp2 domain; logits already scaled by log2e*C^-0.5)
        float mloc = -1e30f;
#pragma unroll
        for (int kt = 0; kt < 4; ++kt)
#pragma unroll
            for (int r = 0; r < 4; ++r) mloc = fmaxf(mloc, st[kt][r]);
        mloc = fmaxf(mloc, __shfl_xor(mloc, 16));
        mloc = fmaxf(mloc, __shfl_xor(mloc, 32));
        float mnew  = fmaxf(m, mloc);
        float alpha = exp2f(m - mnew);
        float ls = 0.f;
#pragma unroll
        for (int kt = 0; kt < 4; ++kt)
#pragma unroll
            for (int r = 0; r < 4; ++r) {
                float p = exp2f(st[kt][r] - mnew);
                st[kt][r] = p;
                ls += p;
            }
        ls += __shfl_xor(ls, 16);
        ls += __shfl_xor(ls, 32);
        l = l * alpha + ls;
        m = mnew;
        // rescale acc: acc rows are q = 4g+r; alpha lives at lane lo==4g+r
#pragma unroll
        for (int r = 0; r < 4; ++r) {
            float ar = __shfl(alpha, g * 4 + r);
#pragma unroll
            for (int ht = 0; ht < 4; ++ht) acc[ht][r] *= ar;
        }
        // P -> LDS (bf16, XOR swizzle: byte = (q*128 + k*2) ^ ((q&7)<<4); 2-way max)
#pragma unroll
        for (int kt = 0; kt < 4; ++kt) {
            bf16x4 pk;
#pragma unroll
            for (int r = 0; r < 4; ++r) pk[r] = (__bf16)st[kt][r];
            int waddr = (lo * 128 + kt * 32 + g * 8) ^ ((lo & 7) << 4);
            *(bf16x4*)(pl + waddr) = pk;
        }
        // PV: A = P[q][k] (lane: q=lo, k=c*32+g*8+j), B = V^T rows (16B/lane)
#pragma unroll
        for (int c = 0; c < 2; ++c) {
            int raddr = (lo * 128 + c * 64 + g * 16) ^ ((lo & 7) << 4);
            bf16x8 pa = *(const bf16x8*)(pl + raddr);
#pragma unroll
            for (int ht = 0; ht < 4; ++ht) {
                bf16x8 vb = *(const bf16x8*)(Vt + (size_t)(b * 64 + ht * 16 + lo) * T_ + k0 + c * 32 + g * 8);
                acc[ht] = MFMA16(pa, vb, acc[ht]);
            }
        }
    }

    float linv = 1.f / l;
#pragma unroll
    for (int r = 0; r < 4; ++r) {
        float lr = __shfl(linv, g * 4 + r);
#pragma unroll
        for (int ht = 0; ht < 4; ++ht)
            out[(size_t)(b * T_ + q0 + 4 * g + r) * H_ + ht * 16 + lo] = acc[ht][r] * lr;
    }
}

// ---------------------------------------------------------------------------
extern "C" void kernel_launch(void* const* d_in, const int* in_sizes, int n_in,
                              void* d_out, int out_size, void* d_ws, size_t ws_size,
                              hipStream_t stream) {
    const float* x  = (const float*)d_in[0];
    const float* Wk = (const float*)d_in[1];
    const float* bk = (const float*)d_in[2];
    const float* Wq = (const float*)d_in[3];
    const float* bq = (const float*)d_in[4];
    const float* Wv = (const float*)d_in[5];
    const float* bv = (const float*)d_in[6];

    char* ws = (char*)d_ws;
    // ws layout: Wt 384KB | Kg 2MB | Qg 2MB | Vt 2MB  (~6.7 MB total)
    __bf16* Wt = (__bf16*)(ws);
    __bf16* Kg = (__bf16*)(ws + 393216);
    __bf16* Qg = (__bf16*)(ws + 393216 + 2097152);
    __bf16* Vt = (__bf16*)(ws + 393216 + 2 * 2097152);
    float* out = (float*)d_out;

    prep_wt<<<768, 256, 0, stream>>>(Wk, Wq, Wv, Wt);
    proj_qkv<<<256, 256, 0, stream>>>(x, Wt, bk, bq, bv, Kg, Qg, Vt);
    attn_fwd<<<B_ * (T_ / 16), 64, 0, stream>>>(Qg, Kg, Vt, out);
}

// Round 2
// 143.759 us; speedup vs baseline: 1.6851x; 1.6851x over previous
//
#include <hip/hip_runtime.h>

// Head: B=4, T=4096, C=1024, H=64. out = softmax(causal((x@Wq+bq)@(x@Wk+bk)^T * C^-0.5)) @ (x@Wv+bv)
#define B_ 4
#define T_ 4096
#define C_ 1024
#define H_ 64
// C^-0.5 * log2(e): folds softmax scale into Q, moves softmax into exp2 domain.
#define QSCALE 0.045084220027780106f

typedef float  f32x4  __attribute__((ext_vector_type(4)));
typedef __bf16 bf16x8 __attribute__((ext_vector_type(8)));
typedef __bf16 bf16x4 __attribute__((ext_vector_type(4)));

#define MFMA16(a, b, c) __builtin_amdgcn_mfma_f32_16x16x32_bf16((a), (b), (c), 0, 0, 0)

// ---------------------------------------------------------------------------
// prep: Wt[mat][n][k] = W_mat[k][n] as bf16, via LDS tile transpose (both sides
// coalesced). grid = 3 mats * 16 k-tiles.
// ---------------------------------------------------------------------------
__global__ __launch_bounds__(256) void prep_wt(const float* __restrict__ Wk,
                                               const float* __restrict__ Wq,
                                               const float* __restrict__ Wv,
                                               __bf16* __restrict__ Wt) {
    __shared__ float tile[64][65];
    int tid = threadIdx.x;
    int mat = blockIdx.x >> 4;
    int k0  = (blockIdx.x & 15) * 64;
    const float* W = (mat == 0) ? Wk : ((mat == 1) ? Wq : Wv);
#pragma unroll
    for (int i = 0; i < 16; ++i) {
        int e = i * 256 + tid;
        int ki = e >> 6, n = e & 63;
        tile[ki][n] = W[(size_t)(k0 + ki) * 64 + n];
    }
    __syncthreads();
#pragma unroll
    for (int i = 0; i < 16; ++i) {
        int e = i * 256 + tid;
        int n = e >> 6, kj = e & 63;
        Wt[(size_t)mat * 65536 + (size_t)n * 1024 + k0 + kj] = (__bf16)tile[kj][n];
    }
}

// ---------------------------------------------------------------------------
// proj: q,k,v = x@W + b.  1024 blocks x 4 waves; block = 16 rows; wave w
// handles k in [w*256, w*256+256) (in-block split-k); LDS f32 combine.
// ---------------------------------------------------------------------------
__global__ __launch_bounds__(256) void proj_qkv(const float* __restrict__ x,
                                                const __bf16* __restrict__ Wt,
                                                const float* __restrict__ bk,
                                                const float* __restrict__ bq,
                                                const float* __restrict__ bv,
                                                __bf16* __restrict__ Kg,
                                                __bf16* __restrict__ Qg,
                                                __bf16* __restrict__ Vt) {
    // pbuf[w][mat] is a 16x64 f32 tile stored with row stride 68 (bank-spread)
    __shared__ float pbuf[4 * 3 * 1088];
    int tid  = threadIdx.x;
    int w    = tid >> 6;
    int lane = tid & 63;
    int lo = lane & 15, g = lane >> 4;

    int row0 = blockIdx.x * 16;
    const float* xrow = x + (size_t)(row0 + lo) * C_;

    f32x4 acc[3][4];
#pragma unroll
    for (int m = 0; m < 3; ++m)
#pragma unroll
        for (int n = 0; n < 4; ++n) acc[m][n] = (f32x4){0.f, 0.f, 0.f, 0.f};

#pragma unroll 2
    for (int ki = 0; ki < 8; ++ki) {
        int kk = w * 256 + ki * 32;
        const float* xp = xrow + kk + g * 8;
        f32x4 a0 = *(const f32x4*)(xp);
        f32x4 a1 = *(const f32x4*)(xp + 4);
        bf16x8 av;
        av[0] = (__bf16)a0[0]; av[1] = (__bf16)a0[1];
        av[2] = (__bf16)a0[2]; av[3] = (__bf16)a0[3];
        av[4] = (__bf16)a1[0]; av[5] = (__bf16)a1[1];
        av[6] = (__bf16)a1[2]; av[7] = (__bf16)a1[3];
#pragma unroll
        for (int mat = 0; mat < 3; ++mat) {
#pragma unroll
            for (int nt = 0; nt < 4; ++nt) {
                bf16x8 bv8 = *(const bf16x8*)(Wt + (size_t)(mat * 64 + nt * 16 + lo) * C_ + kk + g * 8);
                acc[mat][nt] = MFMA16(av, bv8, acc[mat][nt]);
            }
        }
    }

    // partials -> LDS.  C/D layout: col = lo (h sub), row = 4g + r.
#pragma unroll
    for (int mat = 0; mat < 3; ++mat)
#pragma unroll
        for (int nt = 0; nt < 4; ++nt)
#pragma unroll
            for (int r = 0; r < 4; ++r)
                pbuf[(w * 3 + mat) * 1088 + (4 * g + r) * 68 + nt * 16 + lo] = acc[mat][nt][r];
    __syncthreads();

    // combine K (mat 0) and Q (mat 1): coalesced rows of 64
#pragma unroll
    for (int mat = 0; mat < 2; ++mat) {
        const float* bias = (mat == 0) ? bk : bq;
        __bf16* dst = (mat == 0) ? Kg : Qg;
#pragma unroll
        for (int i = 0; i < 4; ++i) {
            int e = i * 256 + tid;
            int r = e >> 6, h = e & 63;
            float v = pbuf[(0 * 3 + mat) * 1088 + r * 68 + h]
                    + pbuf[(1 * 3 + mat) * 1088 + r * 68 + h]
                    + pbuf[(2 * 3 + mat) * 1088 + r * 68 + h]
                    + pbuf[(3 * 3 + mat) * 1088 + r * 68 + h];
            v += bias[h];
            if (mat == 1) v *= QSCALE;
            dst[(size_t)(row0 + r) * H_ + h] = (__bf16)v;
        }
    }
    // combine V (mat 2) -> transposed [B][64][T]; 16 consecutive threads write
    // 16 consecutive t of one h-row (32B chunks).
#pragma unroll
    for (int i = 0; i < 4; ++i) {
        int e = i * 256 + tid;
        int r = e & 15, h = e >> 4;
        float v = pbuf[(0 * 3 + 2) * 1088 + r * 68 + h]
                + pbuf[(1 * 3 + 2) * 1088 + r * 68 + h]
                + pbuf[(2 * 3 + 2) * 1088 + r * 68 + h]
                + pbuf[(3 * 3 + 2) * 1088 + r * 68 + h];
        v += bv[h];
        int gr = row0 + r;
        int b_ = gr >> 12, t0 = gr & (T_ - 1);
        Vt[(size_t)(b_ * 64 + h) * T_ + t0] = (__bf16)v;
    }
}

// ---------------------------------------------------------------------------
// attn: flash attention, 8 waves/block, in-block split-k.
// Block = one 16-row q-tile; wave w processes k-blocks w, w+8, ... (KBLK=64)
// with private online-softmax state; LDS log-sum-exp merge at the end.
// Swapped QK^T: St[k][q] = mfma(K, Q) so softmax rows are lane-local.
// ---------------------------------------------------------------------------
__global__ __launch_bounds__(512) void attn_fwd(const __bf16* __restrict__ Qg,
                                                const __bf16* __restrict__ Kg,
                                                const __bf16* __restrict__ Vt,
                                                float* __restrict__ out) {
    // 8 x 4KB regions: per-wave P-relayout buffer during the loop (first 2KB),
    // then the wave's 16x64 f32 acc partial. + ml[8][16][2].
    __shared__ alignas(16) char smem[8 * 4096 + 8 * 16 * 2 * 4];

    int tid  = threadIdx.x;
    int w    = tid >> 6;
    int lane = tid & 63;
    int lo = lane & 15, g = lane >> 4;

    int bid = blockIdx.x;
    int b   = bid & 3;
    int qt  = 255 - (bid >> 2);                    // heavy tiles launch first
    int q0  = qt * 16;

    char* pl = smem + w * 4096;                    // wave-private P buffer

    // Q as B-fragment: lane holds Q[q0+lo][c*32 + g*8 + j]  (already *QSCALE)
    const __bf16* qp = Qg + (size_t)(b * T_ + q0 + lo) * H_ + g * 8;
    bf16x8 qb0 = *(const bf16x8*)(qp);
    bf16x8 qb1 = *(const bf16x8*)(qp + 32);

    f32x4 acc[4];
#pragma unroll
    for (int ht = 0; ht < 4; ++ht) acc[ht] = (f32x4){0.f, 0.f, 0.f, 0.f};
    float m = -1e30f, l = 0.f;

    int niter = (q0 >> 6) + 1;                     // only last k-block is partial
    for (int kb = w; kb < niter; kb += 8) {
        int k0 = kb << 6;
        f32x4 st[4];
#pragma unroll
        for (int kt = 0; kt < 4; ++kt) {
            const __bf16* kp = Kg + (size_t)(b * T_ + k0 + kt * 16 + lo) * H_ + g * 8;
            bf16x8 ka0 = *(const bf16x8*)(kp);
            bf16x8 ka1 = *(const bf16x8*)(kp + 32);
            f32x4 z = (f32x4){0.f, 0.f, 0.f, 0.f};
            z = MFMA16(ka0, qb0, z);               // St[k][q]: col=q=lo, row=k=4g+r
            z = MFMA16(ka1, qb1, z);
            st[kt] = z;
        }
        if (kb == niter - 1) {                     // causal mask (partial tile)
#pragma unroll
            for (int kt = 0; kt < 4; ++kt)
#pragma unroll
                for (int r = 0; r < 4; ++r) {
                    int kabs = k0 + kt * 16 + 4 * g + r;
                    if (kabs > q0 + lo) st[kt][r] = -1e30f;
                }
        }
        // online softmax (exp2 domain)
        float mloc = -1e30f;
#pragma unroll
        for (int kt = 0; kt < 4; ++kt)
#pragma unroll
            for (int r = 0; r < 4; ++r) mloc = fmaxf(mloc, st[kt][r]);
        mloc = fmaxf(mloc, __shfl_xor(mloc, 16));
        mloc = fmaxf(mloc, __shfl_xor(mloc, 32));
        float mnew  = fmaxf(m, mloc);
        float alpha = exp2f(m - mnew);
        float ls = 0.f;
#pragma unroll
        for (int kt = 0; kt < 4; ++kt)
#pragma unroll
            for (int r = 0; r < 4; ++r) {
                float p = exp2f(st[kt][r] - mnew);
                st[kt][r] = p;
                ls += p;
            }
        ls += __shfl_xor(ls, 16);
        ls += __shfl_xor(ls, 32);
        l = l * alpha + ls;
        m = mnew;
        // rescale acc: acc rows are q = 4g+r; alpha lives at lanes with lo == q
#pragma unroll
        for (int r = 0; r < 4; ++r) {
            float ar = __shfl(alpha, 4 * g + r);
#pragma unroll
            for (int ht = 0; ht < 4; ++ht) acc[ht][r] *= ar;
        }
        // P -> LDS (bf16, XOR swizzle: 2-way max)
#pragma unroll
        for (int kt = 0; kt < 4; ++kt) {
            bf16x4 pk;
#pragma unroll
            for (int r = 0; r < 4; ++r) pk[r] = (__bf16)st[kt][r];
            int waddr = (lo * 128 + kt * 32 + g * 8) ^ ((lo & 7) << 4);
            *(bf16x4*)(pl + waddr) = pk;
        }
        // PV: A = P[q][k], B = V^T rows (16B/lane contiguous)
#pragma unroll
        for (int c = 0; c < 2; ++c) {
            int raddr = (lo * 128 + c * 64 + g * 16) ^ ((lo & 7) << 4);
            bf16x8 pa = *(const bf16x8*)(pl + raddr);
#pragma unroll
            for (int ht = 0; ht < 4; ++ht) {
                bf16x8 vb = *(const bf16x8*)(Vt + (size_t)(b * 64 + ht * 16 + lo) * T_ + k0 + c * 32 + g * 8);
                acc[ht] = MFMA16(pa, vb, acc[ht]);
            }
        }
    }

    // ---- write per-wave partials (reuses the P region; wave-private) ----
    float* ab = (float*)(smem + w * 4096);         // [16][64]
#pragma unroll
    for (int ht = 0; ht < 4; ++ht)
#pragma unroll
        for (int r = 0; r < 4; ++r)
            ab[(4 * g + r) * 64 + ht * 16 + lo] = acc[ht][r];
    float* ml = (float*)(smem + 8 * 4096);         // [8][16][2]
    if (g == 0) {
        ml[(w * 16 + lo) * 2 + 0] = m;
        ml[(w * 16 + lo) * 2 + 1] = l;
    }
    __syncthreads();

    // ---- merge 8 partials: 1024 outputs, 512 threads -> 2 each ----
    const float* fl = (const float*)smem;
#pragma unroll
    for (int i = 0; i < 2; ++i) {
        int e = i * 512 + tid;
        int q = e >> 6, h = e & 63;
        float M = -1e30f;
#pragma unroll
        for (int ww = 0; ww < 8; ++ww) M = fmaxf(M, ml[(ww * 16 + q) * 2]);
        float L = 0.f, O = 0.f;
#pragma unroll
        for (int ww = 0; ww < 8; ++ww) {
            float sc = exp2f(ml[(ww * 16 + q) * 2] - M);
            L += ml[(ww * 16 + q) * 2 + 1] * sc;
            O += fl[ww * 1024 + q * 64 + h] * sc;
        }
        out[(size_t)(b * T_ + q0 + q) * H_ + h] = O / L;
    }
}

// ---------------------------------------------------------------------------
extern "C" void kernel_launch(void* const* d_in, const int* in_sizes, int n_in,
                              void* d_out, int out_size, void* d_ws, size_t ws_size,
                              hipStream_t stream) {
    const float* x  = (const float*)d_in[0];
    const float* Wk = (const float*)d_in[1];
    const float* bk = (const float*)d_in[2];
    const float* Wq = (const float*)d_in[3];
    const float* bq = (const float*)d_in[4];
    const float* Wv = (const float*)d_in[5];
    const float* bv = (const float*)d_in[6];

    char* ws = (char*)d_ws;
    // ws layout: Wt 384KB | Kg 2MB | Qg 2MB | Vt 2MB  (~6.7 MB total)
    __bf16* Wt = (__bf16*)(ws);
    __bf16* Kg = (__bf16*)(ws + 393216);
    __bf16* Qg = (__bf16*)(ws + 393216 + 2097152);
    __bf16* Vt = (__bf16*)(ws + 393216 + 2 * 2097152);
    float* out = (float*)d_out;

    prep_wt<<<48, 256, 0, stream>>>(Wk, Wq, Wv, Wt);
    proj_qkv<<<1024, 256, 0, stream>>>(x, Wt, bk, bq, bv, Kg, Qg, Vt);
    attn_fwd<<<B_ * (T_ / 16), 512, 0, stream>>>(Qg, Kg, Vt, out);
}

// Round 3
// 136.096 us; speedup vs baseline: 1.7799x; 1.0563x over previous
//
#include <hip/hip_runtime.h>

// Head: B=4, T=4096, C=1024, H=64. out = softmax(causal((x@Wq+bq)@(x@Wk+bk)^T * C^-0.5)) @ (x@Wv+bv)
#define B_ 4
#define T_ 4096
#define C_ 1024
#define H_ 64
// C^-0.5 * log2(e): folds softmax scale into Q, moves softmax into exp2 domain.
#define QSCALE 0.045084220027780106f

typedef float  f32x4  __attribute__((ext_vector_type(4)));
typedef __bf16 bf16x8 __attribute__((ext_vector_type(8)));
typedef __bf16 bf16x4 __attribute__((ext_vector_type(4)));

#define MFMA16(a, b, c) __builtin_amdgcn_mfma_f32_16x16x32_bf16((a), (b), (c), 0, 0, 0)

// ---------------------------------------------------------------------------
// prep: Wt[mat][n][k] = W_mat[k][n] as bf16 (LDS tile transpose). 192 blocks.
// ---------------------------------------------------------------------------
__global__ __launch_bounds__(256) void prep_wt(const float* __restrict__ Wk,
                                               const float* __restrict__ Wq,
                                               const float* __restrict__ Wv,
                                               __bf16* __restrict__ Wt) {
    __shared__ float tile[16][65];
    int tid = threadIdx.x;
    int mat = blockIdx.x >> 6;
    int k0  = (blockIdx.x & 63) * 16;
    const float* W = (mat == 0) ? Wk : ((mat == 1) ? Wq : Wv);
#pragma unroll
    for (int i = 0; i < 4; ++i) {
        int e = i * 256 + tid;
        int ki = e >> 6, n = e & 63;
        tile[ki][n] = W[(size_t)(k0 + ki) * 64 + n];
    }
    __syncthreads();
#pragma unroll
    for (int i = 0; i < 4; ++i) {
        int e = i * 256 + tid;
        int n = e >> 4, kj = e & 15;
        Wt[(size_t)mat * 65536 + (size_t)n * 1024 + k0 + kj] = (__bf16)tile[kj][n];
    }
}

// ---------------------------------------------------------------------------
// proj: 1024 blocks x 4 waves, block = 16 rows, wave w = output cols
// [16w,16w+16) of K,Q,V (3 MFMA/iter). A-frag shared across waves via L1.
// No LDS, no barriers -> high occupancy (16 waves/CU).
// ---------------------------------------------------------------------------
__global__ __launch_bounds__(256, 4) void proj_qkv(const float* __restrict__ x,
                                                   const __bf16* __restrict__ Wt,
                                                   const float* __restrict__ bk,
                                                   const float* __restrict__ bq,
                                                   const float* __restrict__ bv,
                                                   __bf16* __restrict__ Kg,
                                                   __bf16* __restrict__ Qg,
                                                   __bf16* __restrict__ Vt) {
    int tid  = threadIdx.x;
    int w    = tid >> 6;
    int lane = tid & 63;
    int lo = lane & 15, g = lane >> 4;

    int row0 = blockIdx.x * 16;
    const float*  xrow  = x  + (size_t)(row0 + lo) * C_;
    const __bf16* wbase = Wt + (size_t)(w * 16 + lo) * C_;

    f32x4 acc0 = (f32x4){0.f, 0.f, 0.f, 0.f};
    f32x4 acc1 = (f32x4){0.f, 0.f, 0.f, 0.f};
    f32x4 acc2 = (f32x4){0.f, 0.f, 0.f, 0.f};

#pragma unroll 4
    for (int kk = 0; kk < C_; kk += 32) {
        const float* xp = xrow + kk + g * 8;
        f32x4 a0 = *(const f32x4*)(xp);
        f32x4 a1 = *(const f32x4*)(xp + 4);
        bf16x8 av;
        av[0] = (__bf16)a0[0]; av[1] = (__bf16)a0[1];
        av[2] = (__bf16)a0[2]; av[3] = (__bf16)a0[3];
        av[4] = (__bf16)a1[0]; av[5] = (__bf16)a1[1];
        av[6] = (__bf16)a1[2]; av[7] = (__bf16)a1[3];
        acc0 = MFMA16(av, *(const bf16x8*)(wbase + kk + g * 8),          acc0);
        acc1 = MFMA16(av, *(const bf16x8*)(wbase + 65536 + kk + g * 8),  acc1);
        acc2 = MFMA16(av, *(const bf16x8*)(wbase + 131072 + kk + g * 8), acc2);
    }

    // epilogue. C/D layout: col = lo (h sub), row = 4g + r.
    int h = w * 16 + lo;
    float bks = bk[h], bqs = bq[h], bvs = bv[h];
    int b_   = row0 >> 12;
    int tloc = row0 & (T_ - 1);
#pragma unroll
    for (int r = 0; r < 4; ++r) {
        Kg[(size_t)(row0 + 4 * g + r) * H_ + h] = (__bf16)(acc0[r] + bks);
        Qg[(size_t)(row0 + 4 * g + r) * H_ + h] = (__bf16)((acc1[r] + bqs) * QSCALE);
    }
    bf16x4 pv;
#pragma unroll
    for (int r = 0; r < 4; ++r) pv[r] = (__bf16)(acc2[r] + bvs);
    *(bf16x4*)(Vt + (size_t)(b_ * 64 + h) * T_ + tloc + 4 * g) = pv;
}

// ---------------------------------------------------------------------------
// attn: 256 blocks x 8 waves. Block = low granule i (32 rows) + high granule
// 127-i (32 rows) -> balanced causal work. Wave (t,p): t = 16-row tile
// (L0,L1,H0,H1), p = kb parity (2-way split-k). K/V kb-tiles staged in LDS
// (XOR swizzle, reg-staged), all same-parity waves share the staged tile.
// 2-way LSE merge in LDS at the end.
// ---------------------------------------------------------------------------
__global__ __launch_bounds__(512, 2) void attn_fwd(const __bf16* __restrict__ Qg,
                                                   const __bf16* __restrict__ Kg,
                                                   const __bf16* __restrict__ Vt,
                                                   float* __restrict__ out) {
    // [0,32768)   K tiles: [buf][par] 4 x 8KB
    // [32768,65536) V tiles: [buf][par] 4 x 8KB
    // [65536,81920) P relayout: 8 waves x 2KB
    // merge reuse: [0,32768) partials 8 x 4KB, ml at 65536
    __shared__ alignas(16) char smem[81920];

    int tid  = threadIdx.x;
    int w    = tid >> 6;
    int lane = tid & 63;
    int lo = lane & 15, g = lane >> 4;
    int t = w >> 1, p = w & 1;

    int bid = blockIdx.x;
    int b   = bid & 3;
    int blk = bid >> 2;                            // 0..63

    int q0 = (t < 2) ? (32 * blk + 16 * t) : (4064 - 32 * blk + 16 * (t - 2));
    int kbmaxw = (q0 + 15) >> 6;
    int NKB = ((4095 - 32 * blk) >> 6) + 1;        // high tiles dominate

    // staging indices (block-wide sweep: 512 threads x 16B = one 8KB tile)
    int srow = tid >> 3;
    int scol = ((tid & 7) * 16) ^ ((srow & 7) << 4);
    const char* kgb = (const char*)Kg + (size_t)b * T_ * 128;
    const char* vgb = (const char*)Vt + (size_t)b * 64 * T_ * 2;

    f32x4 kreg0, kreg1, vreg0, vreg1;
    // prologue: stage kb=0 (par0) and kb=1 (par1) into buf0
    kreg0 = *(const f32x4*)(kgb + (size_t)0 * 8192 + tid * 16);
    vreg0 = *(const f32x4*)(vgb + (size_t)srow * T_ * 2 + 0 * 128 + (tid & 7) * 16);
    if (NKB > 1) {
        kreg1 = *(const f32x4*)(kgb + (size_t)1 * 8192 + tid * 16);
        vreg1 = *(const f32x4*)(vgb + (size_t)srow * T_ * 2 + 1 * 128 + (tid & 7) * 16);
    }
    *(f32x4*)(smem + 0 * 8192 + srow * 128 + scol) = kreg0;
    *(f32x4*)(smem + 32768 + 0 * 8192 + srow * 128 + scol) = vreg0;
    if (NKB > 1) {
        *(f32x4*)(smem + 1 * 8192 + srow * 128 + scol) = kreg1;
        *(f32x4*)(smem + 32768 + 1 * 8192 + srow * 128 + scol) = vreg1;
    }
    __syncthreads();

    // Q as B-fragment (already *QSCALE)
    const __bf16* qp = Qg + (size_t)(b * T_ + q0 + lo) * H_ + g * 8;
    bf16x8 qb0 = *(const bf16x8*)(qp);
    bf16x8 qb1 = *(const bf16x8*)(qp + 32);

    char* pl = smem + 65536 + w * 2048;            // wave-private P buffer
    int sw = (lo & 7) << 4;                        // frag-read swizzle

    f32x4 acc[4];
#pragma unroll
    for (int ht = 0; ht < 4; ++ht) acc[ht] = (f32x4){0.f, 0.f, 0.f, 0.f};
    float m = -1e30f, l = 0.f;

    int S = (NKB + 1) >> 1;
    int cur = 0;
    for (int s = 0; s < S; ++s) {
        int kb2 = 2 * s + 2;
        bool st0 = kb2 < NKB, st1 = kb2 + 1 < NKB;
        if (st0) {
            kreg0 = *(const f32x4*)(kgb + (size_t)kb2 * 8192 + tid * 16);
            vreg0 = *(const f32x4*)(vgb + (size_t)srow * T_ * 2 + (size_t)kb2 * 128 + (tid & 7) * 16);
        }
        if (st1) {
            kreg1 = *(const f32x4*)(kgb + (size_t)(kb2 + 1) * 8192 + tid * 16);
            vreg1 = *(const f32x4*)(vgb + (size_t)srow * T_ * 2 + (size_t)(kb2 + 1) * 128 + (tid & 7) * 16);
        }

        int mykb = 2 * s + p;
        if (mykb <= kbmaxw) {
            const char* kbase = smem + (cur * 2 + p) * 8192;
            const char* vbase = smem + 32768 + (cur * 2 + p) * 8192;
            f32x4 st[4];
#pragma unroll
            for (int kt = 0; kt < 4; ++kt) {
                int krow = kt * 16 + lo;
                bf16x8 ka0 = *(const bf16x8*)(kbase + krow * 128 + ((g * 16) ^ sw));
                bf16x8 ka1 = *(const bf16x8*)(kbase + krow * 128 + ((64 + g * 16) ^ sw));
                f32x4 z = (f32x4){0.f, 0.f, 0.f, 0.f};
                z = MFMA16(ka0, qb0, z);           // St[k][q]: col=q=lo, row=k=4g+r
                z = MFMA16(ka1, qb1, z);
                st[kt] = z;
            }
            if (mykb == kbmaxw) {                  // causal mask (diagonal tile)
#pragma unroll
                for (int kt = 0; kt < 4; ++kt)
#pragma unroll
                    for (int r = 0; r < 4; ++r) {
                        int kabs = mykb * 64 + kt * 16 + 4 * g + r;
                        if (kabs > q0 + lo) st[kt][r] = -1e30f;
                    }
            }
            // online softmax (exp2 domain)
            float mloc = -1e30f;
#pragma unroll
            for (int kt = 0; kt < 4; ++kt)
#pragma unroll
                for (int r = 0; r < 4; ++r) mloc = fmaxf(mloc, st[kt][r]);
            mloc = fmaxf(mloc, __shfl_xor(mloc, 16));
            mloc = fmaxf(mloc, __shfl_xor(mloc, 32));
            float mnew  = fmaxf(m, mloc);
            float alpha = exp2f(m - mnew);
            float ls = 0.f;
#pragma unroll
            for (int kt = 0; kt < 4; ++kt)
#pragma unroll
                for (int r = 0; r < 4; ++r) {
                    float pe = exp2f(st[kt][r] - mnew);
                    st[kt][r] = pe;
                    ls += pe;
                }
            ls += __shfl_xor(ls, 16);
            ls += __shfl_xor(ls, 32);
            l = l * alpha + ls;
            m = mnew;
#pragma unroll
            for (int r = 0; r < 4; ++r) {
                float ar = __shfl(alpha, 4 * g + r);
#pragma unroll
                for (int ht = 0; ht < 4; ++ht) acc[ht][r] *= ar;
            }
            // P -> LDS (wave-private, XOR swizzle)
#pragma unroll
            for (int kt = 0; kt < 4; ++kt) {
                bf16x4 pk;
#pragma unroll
                for (int r = 0; r < 4; ++r) pk[r] = (__bf16)st[kt][r];
                int waddr = (lo * 128 + kt * 32 + g * 8) ^ ((lo & 7) << 4);
                *(bf16x4*)(pl + waddr) = pk;
            }
            // PV: A = P[q][k], B = V rows from LDS
#pragma unroll
            for (int c = 0; c < 2; ++c) {
                int raddr = (lo * 128 + c * 64 + g * 16) ^ ((lo & 7) << 4);
                bf16x8 pa = *(const bf16x8*)(pl + raddr);
#pragma unroll
                for (int ht = 0; ht < 4; ++ht) {
                    int vrow = ht * 16 + lo;
                    bf16x8 vb = *(const bf16x8*)(vbase + vrow * 128 + ((c * 64 + g * 16) ^ sw));
                    acc[ht] = MFMA16(pa, vb, acc[ht]);
                }
            }
        }

        if (st0) {
            *(f32x4*)(smem + ((cur ^ 1) * 2 + 0) * 8192 + srow * 128 + scol) = kreg0;
            *(f32x4*)(smem + 32768 + ((cur ^ 1) * 2 + 0) * 8192 + srow * 128 + scol) = vreg0;
        }
        if (st1) {
            *(f32x4*)(smem + ((cur ^ 1) * 2 + 1) * 8192 + srow * 128 + scol) = kreg1;
            *(f32x4*)(smem + 32768 + ((cur ^ 1) * 2 + 1) * 8192 + srow * 128 + scol) = vreg1;
        }
        __syncthreads();
        cur ^= 1;
    }

    // ---- 2-way LSE merge (reuse K/V LDS region) ----
    float* part = (float*)(smem) + w * 1024;       // [16][64]
#pragma unroll
    for (int ht = 0; ht < 4; ++ht)
#pragma unroll
        for (int r = 0; r < 4; ++r)
            part[(4 * g + r) * 64 + ht * 16 + lo] = acc[ht][r];
    float* ml = (float*)(smem + 65536);            // [8][16][2]
    if (g == 0) {
        ml[(w * 16 + lo) * 2 + 0] = m;
        ml[(w * 16 + lo) * 2 + 1] = l;
    }
    __syncthreads();

    const float* fl = (const float*)smem;
#pragma unroll
    for (int j = 0; j < 8; ++j) {
        int e = j * 512 + tid;                     // 4096 outputs
        int tt = e >> 10, qq = (e >> 6) & 15, h = e & 63;
        int w0 = tt * 2, w1 = w0 + 1;
        float m0 = ml[(w0 * 16 + qq) * 2], l0 = ml[(w0 * 16 + qq) * 2 + 1];
        float m1 = ml[(w1 * 16 + qq) * 2], l1 = ml[(w1 * 16 + qq) * 2 + 1];
        float M  = fmaxf(m0, m1);
        float e0 = exp2f(m0 - M), e1 = exp2f(m1 - M);
        float L  = l0 * e0 + l1 * e1;
        float O  = fl[w0 * 1024 + qq * 64 + h] * e0 + fl[w1 * 1024 + qq * 64 + h] * e1;
        int qg = ((tt < 2) ? (32 * blk + 16 * tt) : (4064 - 32 * blk + 16 * (tt - 2))) + qq;
        out[(size_t)(b * T_ + qg) * H_ + h] = O / L;
    }
}

// ---------------------------------------------------------------------------
extern "C" void kernel_launch(void* const* d_in, const int* in_sizes, int n_in,
                              void* d_out, int out_size, void* d_ws, size_t ws_size,
                              hipStream_t stream) {
    const float* x  = (const float*)d_in[0];
    const float* Wk = (const float*)d_in[1];
    const float* bk = (const float*)d_in[2];
    const float* Wq = (const float*)d_in[3];
    const float* bq = (const float*)d_in[4];
    const float* Wv = (const float*)d_in[5];
    const float* bv = (const float*)d_in[6];

    char* ws = (char*)d_ws;
    // ws layout: Wt 384KB | Kg 2MB | Qg 2MB | Vt 2MB
    __bf16* Wt = (__bf16*)(ws);
    __bf16* Kg = (__bf16*)(ws + 393216);
    __bf16* Qg = (__bf16*)(ws + 393216 + 2097152);
    __bf16* Vt = (__bf16*)(ws + 393216 + 2 * 2097152);
    float* out = (float*)d_out;

    prep_wt<<<192, 256, 0, stream>>>(Wk, Wq, Wv, Wt);
    proj_qkv<<<1024, 256, 0, stream>>>(x, Wt, bk, bq, bv, Kg, Qg, Vt);
    attn_fwd<<<256, 512, 0, stream>>>(Qg, Kg, Vt, out);
}